// Round 3
// baseline (4198.535 us; speedup 1.0000x reference)
//
#include <hip/hip_runtime.h>
#include <hip/hip_bf16.h>

// ---------------------------------------------------------------------------
// 2-layer tanh RNN + FC head on MI355X (gfx950).
// Round 3: fused dual-layer persistent recurrence — layer 1 runs wavefront-
// pipelined one step behind layer 0, computing pre1 = h0_t @ W_ih1^T on the
// fly with register-stationary weights (both W_ih1 and W_hh1). Critical path
// drops from 1024 to ~513 sync steps, and the pre1 GEMM disappears.
//   B=64 S=512 I=256 H=1024 O=256
// ---------------------------------------------------------------------------

typedef __attribute__((ext_vector_type(4))) float f32x4;
typedef __attribute__((ext_vector_type(8))) short bf16x8;
typedef __attribute__((ext_vector_type(4))) int   i32x4;
typedef __attribute__((ext_vector_type(4))) short s16x4;

#define B_  64
#define S_  512
#define I_  256
#define H_  1024
#define O_  256
#define M_  (B_ * S_)     // 32768
#define SH_ (S_ * H_)     // 524288 (row stride of h-seq / pre in elements)

static __device__ __forceinline__ unsigned short f2bf(float f) {
  union { float f; unsigned u; } v; v.f = f;
  unsigned r = v.u + 0x7fffu + ((v.u >> 16) & 1u);   // RNE
  return (unsigned short)(r >> 16);
}
static __device__ __forceinline__ float bf2f(unsigned short b) {
  union { unsigned u; float f; } v; v.u = ((unsigned)b) << 16;
  return v.f;
}
static __device__ __forceinline__ float tanh_fast(float x) {
  float e = __expf(2.f * x);
  return 1.f - 2.f / (e + 1.f);
}

// ---------------- f32 -> bf16 conversion (vectorized) ----------------------
__global__ void cvt_bf16(const float* __restrict__ src,
                         unsigned short* __restrict__ dst, int n4) {
  int i = blockIdx.x * blockDim.x + threadIdx.x;
  if (i < n4) {
    f32x4 v = ((const f32x4*)src)[i];
    s16x4 o;
    o[0] = (short)f2bf(v[0]); o[1] = (short)f2bf(v[1]);
    o[2] = (short)f2bf(v[2]); o[3] = (short)f2bf(v[3]);
    ((s16x4*)dst)[i] = o;
  }
}

// ---------------- big MFMA GEMM: C[M,N] = A[M,K]@W[N,K]^T + b1 (+b2) -------
// 128x128 tile, BK=32, 256 thr (4 waves). BF16OUT selects output dtype.
template <bool BF16OUT>
__global__ __launch_bounds__(256)
void gemm_bf16(const unsigned short* __restrict__ A,
               const unsigned short* __restrict__ W,
               const float* __restrict__ b1, const float* __restrict__ b2,
               void* __restrict__ Cv, int Mx, int Nx, int Kx) {
  __shared__ __align__(16) unsigned short As[128 * 40];
  __shared__ __align__(16) unsigned short Bs[128 * 40];
  const int tid  = threadIdx.x;
  const int m0   = blockIdx.y * 128;
  const int n0   = blockIdx.x * 128;
  const int w    = tid >> 6, lane = tid & 63;
  const int quad = lane >> 4, l15 = lane & 15;
  const int wm = (w & 1) * 64, wn = (w >> 1) * 64;

  f32x4 acc[4][4] = {};

  for (int k0 = 0; k0 < Kx; k0 += 32) {
#pragma unroll
    for (int i = 0; i < 2; ++i) {
      int c = tid + i * 256;
      int row = c >> 2, kc = c & 3;
      *(i32x4*)&As[row * 40 + kc * 8] =
          *(const i32x4*)&A[(size_t)(m0 + row) * Kx + k0 + kc * 8];
      *(i32x4*)&Bs[row * 40 + kc * 8] =
          *(const i32x4*)&W[(size_t)(n0 + row) * Kx + k0 + kc * 8];
    }
    __syncthreads();
    bf16x8 af[4], bg[4];
#pragma unroll
    for (int im = 0; im < 4; ++im)
      af[im] = *(const bf16x8*)&As[(wm + im * 16 + l15) * 40 + quad * 8];
#pragma unroll
    for (int in = 0; in < 4; ++in)
      bg[in] = *(const bf16x8*)&Bs[(wn + in * 16 + l15) * 40 + quad * 8];
#pragma unroll
    for (int im = 0; im < 4; ++im)
#pragma unroll
      for (int in = 0; in < 4; ++in)
        acc[im][in] = __builtin_amdgcn_mfma_f32_16x16x32_bf16(
            af[im], bg[in], acc[im][in], 0, 0, 0);
    __syncthreads();
  }

#pragma unroll
  for (int in = 0; in < 4; ++in) {
    int n = n0 + wn + in * 16 + l15;
    float bv = b1 ? b1[n] : 0.f;
    if (b2) bv += b2[n];
#pragma unroll
    for (int im = 0; im < 4; ++im) {
      int mb = m0 + wm + im * 16 + quad * 4;   // C/D: row = quad*4+reg, col = l15
#pragma unroll
      for (int r = 0; r < 4; ++r) {
        float val = acc[im][in][r] + bv;
        size_t o = (size_t)(mb + r) * Nx + n;
        if (BF16OUT) ((unsigned short*)Cv)[o] = f2bf(val);
        else         ((float*)Cv)[o] = val;
      }
    }
  }
}

// ---------------- fused dual-layer persistent recurrence -------------------
// 128 WGs x 256 thr, all co-resident (1 block/CU at <=512 VGPR).
//   bx in [0,64):  layer 0 WG — h0_t = tanh(pre0_t + h0_{t-1}@Whh0^T)
//   bx in [64,128): layer 1 WG — h1_t = tanh(b + h0_t@Wih1^T + h1_{t-1}@Whh1^T)
// Group g = id>>4 owns batches [16g,16g+16); member j = id&15 owns cols
// [64j,64j+64); wave w owns k-slice [256w,256w+256) (split-K via LDS reduce).
// All weight fragments register-stationary for the full 512-step loop.
// Sync: per-(layer,group,step) counters; agent-scope h stores drained by the
// epilogue __syncthreads (vmcnt(0)) before the flag add; consumers spin
// relaxed (all threads — no barrier on the wait path) then agent-acquire
// fence before loading h.
__global__ __launch_bounds__(256, 1)
void rnn_fused(const unsigned short* __restrict__ Whh0,   // [H,H] bf16
               const unsigned short* __restrict__ Wih1,   // [H,H] bf16
               const unsigned short* __restrict__ Whh1,   // [H,H] bf16
               const unsigned short* __restrict__ pre0,   // [B,S,H] bf16
               const float* __restrict__ b_ih_1,
               const float* __restrict__ b_hh_1,
               unsigned short* __restrict__ h0seq,        // [B,S,H] bf16
               unsigned short* __restrict__ h1seq,        // [B,S,H] bf16
               unsigned int* __restrict__ flags)          // [2][4][S] zeroed
{
  const int bx   = blockIdx.x;
  const int L    = bx >> 6;         // 0: layer-0 WG, 1: layer-1 WG
  const int id   = bx & 63;
  const int g    = id >> 4;         // batch group 0..3
  const int n0   = (id & 15) * 64;  // column block
  const int tid  = threadIdx.x;
  const int w    = tid >> 6;        // wave = k-slice
  const int lane = tid & 63;
  const int quad = lane >> 4, l15 = lane & 15;

  __shared__ __align__(16) float q[4][4][16][20];  // [wave][ntile][col][4r pad20]

  unsigned int* const f0 = flags + g * S_;
  unsigned int* const f1 = flags + 4 * S_ + g * S_;

  if (L == 0) {
    // ---------------- layer 0 ----------------
    bf16x8 Wf[4][8];
    {
      const unsigned short* wp = Whh0 + (size_t)(n0 + l15) * H_ + w * 256 + quad * 8;
#pragma unroll
      for (int i = 0; i < 4; ++i)
#pragma unroll
        for (int kk = 0; kk < 8; ++kk)
          Wf[i][kk] = *(const bf16x8*)(wp + (size_t)i * 16 * H_ + kk * 32);
    }

    for (int t = 0; t < S_; ++t) {
      // prefetch pre0 (independent of recurrence — overlaps the wait)
      float pv[4];
      {
        const unsigned short* pp = pre0 + (size_t)(g * 16 + quad * 4) * SH_ +
                                   (size_t)t * H_ + n0 + w * 16 + l15;
#pragma unroll
        for (int r = 0; r < 4; ++r) pv[r] = bf2f(pp[(size_t)r * SH_]);
      }

      f32x4 acc[4] = {};
      if (t > 0) {
        while (__hip_atomic_load(&f0[t - 1], __ATOMIC_RELAXED,
                                 __HIP_MEMORY_SCOPE_AGENT) < 16u) {}
        __builtin_amdgcn_fence(__ATOMIC_ACQUIRE, "agent");
        const unsigned short* hp = h0seq + (size_t)(g * 16 + l15) * SH_ +
                                   (size_t)(t - 1) * H_ + w * 256 + quad * 8;
        bf16x8 Af[8];
#pragma unroll
        for (int kk = 0; kk < 8; ++kk) Af[kk] = *(const bf16x8*)(hp + kk * 32);
#pragma unroll
        for (int kk = 0; kk < 8; ++kk)
#pragma unroll
          for (int i = 0; i < 4; ++i)
            acc[i] = __builtin_amdgcn_mfma_f32_16x16x32_bf16(
                Af[kk], Wf[i][kk], acc[i], 0, 0, 0);
      }

      // split-K reduce
#pragma unroll
      for (int i = 0; i < 4; ++i) *(f32x4*)&q[w][i][l15][quad * 4] = acc[i];
      __syncthreads();
      f32x4 s = {};
#pragma unroll
      for (int wp2 = 0; wp2 < 4; ++wp2) {
        f32x4 v = *(const f32x4*)&q[wp2][w][l15][quad * 4];
#pragma unroll
        for (int r = 0; r < 4; ++r) s[r] += v[r];
      }

#pragma unroll
      for (int r = 0; r < 4; ++r) {
        unsigned short hb = f2bf(tanh_fast(pv[r] + s[r]));
        size_t o = (size_t)(g * 16 + quad * 4 + r) * SH_ + (size_t)t * H_ +
                   n0 + w * 16 + l15;
        __hip_atomic_store(&h0seq[o], hb, __ATOMIC_RELAXED,
                           __HIP_MEMORY_SCOPE_AGENT);
      }
      __syncthreads();   // drains vmcnt(0); also WAR on q
      if (tid == 0)
        __hip_atomic_fetch_add(&f0[t], 1u, __ATOMIC_RELAXED,
                               __HIP_MEMORY_SCOPE_AGENT);
    }
  } else {
    // ---------------- layer 1 (lags layer 0 by one step) ----------------
    bf16x8 Wi[4][8], Wr[4][8];
    {
      const unsigned short* wpi = Wih1 + (size_t)(n0 + l15) * H_ + w * 256 + quad * 8;
      const unsigned short* wpr = Whh1 + (size_t)(n0 + l15) * H_ + w * 256 + quad * 8;
#pragma unroll
      for (int i = 0; i < 4; ++i)
#pragma unroll
        for (int kk = 0; kk < 8; ++kk) {
          Wi[i][kk] = *(const bf16x8*)(wpi + (size_t)i * 16 * H_ + kk * 32);
          Wr[i][kk] = *(const bf16x8*)(wpr + (size_t)i * 16 * H_ + kk * 32);
        }
    }
    const int ncol = n0 + w * 16 + l15;          // epilogue column of this lane
    const float bias = b_ih_1[ncol] + b_hh_1[ncol];

    for (int t = 0; t < S_; ++t) {
      f32x4 acc[4] = {};

      // recurrent part first — h1_{t-1} is usually long ready
      if (t > 0) {
        while (__hip_atomic_load(&f1[t - 1], __ATOMIC_RELAXED,
                                 __HIP_MEMORY_SCOPE_AGENT) < 16u) {}
        __builtin_amdgcn_fence(__ATOMIC_ACQUIRE, "agent");
        const unsigned short* hp = h1seq + (size_t)(g * 16 + l15) * SH_ +
                                   (size_t)(t - 1) * H_ + w * 256 + quad * 8;
        bf16x8 Af[8];
#pragma unroll
        for (int kk = 0; kk < 8; ++kk) Af[kk] = *(const bf16x8*)(hp + kk * 32);
#pragma unroll
        for (int kk = 0; kk < 8; ++kk)
#pragma unroll
          for (int i = 0; i < 4; ++i)
            acc[i] = __builtin_amdgcn_mfma_f32_16x16x32_bf16(
                Af[kk], Wr[i][kk], acc[i], 0, 0, 0);
      }

      // input-projection part — the actual critical wait (h0_t)
      {
        while (__hip_atomic_load(&f0[t], __ATOMIC_RELAXED,
                                 __HIP_MEMORY_SCOPE_AGENT) < 16u) {}
        __builtin_amdgcn_fence(__ATOMIC_ACQUIRE, "agent");
        const unsigned short* hp = h0seq + (size_t)(g * 16 + l15) * SH_ +
                                   (size_t)t * H_ + w * 256 + quad * 8;
        bf16x8 Af[8];
#pragma unroll
        for (int kk = 0; kk < 8; ++kk) Af[kk] = *(const bf16x8*)(hp + kk * 32);
#pragma unroll
        for (int kk = 0; kk < 8; ++kk)
#pragma unroll
          for (int i = 0; i < 4; ++i)
            acc[i] = __builtin_amdgcn_mfma_f32_16x16x32_bf16(
                Af[kk], Wi[i][kk], acc[i], 0, 0, 0);
      }

      // split-K reduce
#pragma unroll
      for (int i = 0; i < 4; ++i) *(f32x4*)&q[w][i][l15][quad * 4] = acc[i];
      __syncthreads();
      f32x4 s = {};
#pragma unroll
      for (int wp2 = 0; wp2 < 4; ++wp2) {
        f32x4 v = *(const f32x4*)&q[wp2][w][l15][quad * 4];
#pragma unroll
        for (int r = 0; r < 4; ++r) s[r] += v[r];
      }

#pragma unroll
      for (int r = 0; r < 4; ++r) {
        unsigned short hb = f2bf(tanh_fast(bias + s[r]));
        size_t o = (size_t)(g * 16 + quad * 4 + r) * SH_ + (size_t)t * H_ +
                   n0 + w * 16 + l15;
        __hip_atomic_store(&h1seq[o], hb, __ATOMIC_RELAXED,
                           __HIP_MEMORY_SCOPE_AGENT);
      }
      __syncthreads();
      if (tid == 0)
        __hip_atomic_fetch_add(&f1[t], 1u, __ATOMIC_RELAXED,
                               __HIP_MEMORY_SCOPE_AGENT);
    }
  }
}

// ---------------------------------------------------------------------------
extern "C" void kernel_launch(void* const* d_in, const int* in_sizes, int n_in,
                              void* d_out, int out_size, void* d_ws, size_t ws_size,
                              hipStream_t stream) {
  const float* x      = (const float*)d_in[0];
  const float* W_ih_0 = (const float*)d_in[1];
  const float* W_hh_0 = (const float*)d_in[2];
  const float* b_ih_0 = (const float*)d_in[3];
  const float* b_hh_0 = (const float*)d_in[4];
  const float* W_ih_1 = (const float*)d_in[5];
  const float* W_hh_1 = (const float*)d_in[6];
  const float* b_ih_1 = (const float*)d_in[7];
  const float* b_hh_1 = (const float*)d_in[8];
  const float* fc_w   = (const float*)d_in[9];
  const float* fc_b   = (const float*)d_in[10];
  float* out = (float*)d_out;

  char* ws = (char*)d_ws;
  size_t off = 0;
  auto alloc = [&](size_t bytes) { char* p = ws + off; off += (bytes + 255) & ~(size_t)255; return p; };
  unsigned short* xb    = (unsigned short*)alloc((size_t)M_ * I_ * 2);   // 16.8 MB
  unsigned short* wih0b = (unsigned short*)alloc((size_t)H_ * I_ * 2);
  unsigned short* whh0b = (unsigned short*)alloc((size_t)H_ * H_ * 2);
  unsigned short* wih1b = (unsigned short*)alloc((size_t)H_ * H_ * 2);
  unsigned short* whh1b = (unsigned short*)alloc((size_t)H_ * H_ * 2);
  unsigned short* fcwb  = (unsigned short*)alloc((size_t)O_ * H_ * 2);
  unsigned int*   flags = (unsigned int*)alloc(2 * 4 * S_ * 4);          // 16 KB
  unsigned short* pre0b = (unsigned short*)alloc((size_t)M_ * H_ * 2);   // 67 MB
  unsigned short* h0seq = (unsigned short*)alloc((size_t)M_ * H_ * 2);   // 67 MB
  unsigned short* h1seq = (unsigned short*)alloc((size_t)M_ * H_ * 2);   // 67 MB
  // total ~225 MB — same footprint as the Round-1 kernel (known to fit)

  hipMemsetAsync(flags, 0, 2 * 4 * S_ * 4, stream);

  auto cvt = [&](const float* s, unsigned short* d, int n) {
    int n4 = n / 4;
    cvt_bf16<<<(n4 + 255) / 256, 256, 0, stream>>>(s, d, n4);
  };
  cvt(x,      xb,    M_ * I_);
  cvt(W_ih_0, wih0b, H_ * I_);
  cvt(W_hh_0, whh0b, H_ * H_);
  cvt(W_ih_1, wih1b, H_ * H_);
  cvt(W_hh_1, whh1b, H_ * H_);
  cvt(fc_w,   fcwb,  O_ * H_);

  // pre0 = x @ W_ih0^T + b_ih0 + b_hh0  (bf16 out)
  gemm_bf16<true><<<dim3(H_ / 128, M_ / 128), 256, 0, stream>>>(
      xb, wih0b, b_ih_0, b_hh_0, pre0b, M_, H_, I_);

  // fused dual-layer recurrence (layer 1 pipelined one step behind layer 0)
  rnn_fused<<<128, 256, 0, stream>>>(whh0b, wih1b, whh1b, pre0b,
                                     b_ih_1, b_hh_1, h0seq, h1seq, flags);

  // FC head
  gemm_bf16<false><<<dim3(O_ / 128, M_ / 128), 256, 0, stream>>>(
      h1seq, fcwb, fc_b, nullptr, out, M_, O_, H_);
}

// Round 4
// 2815.442 us; speedup vs baseline: 1.4913x; 1.4913x over previous
//
#include <hip/hip_runtime.h>
#include <hip/hip_bf16.h>

// ---------------------------------------------------------------------------
// 2-layer tanh RNN + FC head on MI355X (gfx950).
// Round 4: fused dual-layer pipeline, weights pinned in VGPRs via asm,
// round-2 sync discipline (tid0 poll + fence + barrier).
//   B=64 S=512 I=256 H=1024 O=256
//   layer-0: 64 WGs, 64 cols each (Whh0 = 128 VGPR/lane, pinned)
//   layer-1: 128 WGs, 32 cols each (Wih1+Whh1 = 128 VGPR/lane, pinned),
//            runs one step behind layer 0 (pre1 GEMM eliminated)
// ---------------------------------------------------------------------------

typedef __attribute__((ext_vector_type(4))) float f32x4;
typedef __attribute__((ext_vector_type(8))) short bf16x8;
typedef __attribute__((ext_vector_type(4))) int   i32x4;
typedef __attribute__((ext_vector_type(4))) short s16x4;

#define B_  64
#define S_  512
#define I_  256
#define H_  1024
#define O_  256
#define M_  (B_ * S_)     // 32768
#define SH_ (S_ * H_)     // 524288 (row stride of h-seq / pre in elements)

static __device__ __forceinline__ unsigned short f2bf(float f) {
  union { float f; unsigned u; } v; v.f = f;
  unsigned r = v.u + 0x7fffu + ((v.u >> 16) & 1u);   // RNE
  return (unsigned short)(r >> 16);
}
static __device__ __forceinline__ float bf2f(unsigned short b) {
  union { unsigned u; float f; } v; v.u = ((unsigned)b) << 16;
  return v.f;
}
static __device__ __forceinline__ float tanh_fast(float x) {
  float e = __expf(2.f * x);
  return 1.f - 2.f / (e + 1.f);
}
static __device__ __forceinline__ bf16x8 as_bf16x8(i32x4 v) {
  union { i32x4 i; bf16x8 b; } u; u.i = v; return u.b;
}

// ---------------- f32 -> bf16 conversion (vectorized) ----------------------
__global__ void cvt_bf16(const float* __restrict__ src,
                         unsigned short* __restrict__ dst, int n4) {
  int i = blockIdx.x * blockDim.x + threadIdx.x;
  if (i < n4) {
    f32x4 v = ((const f32x4*)src)[i];
    s16x4 o;
    o[0] = (short)f2bf(v[0]); o[1] = (short)f2bf(v[1]);
    o[2] = (short)f2bf(v[2]); o[3] = (short)f2bf(v[3]);
    ((s16x4*)dst)[i] = o;
  }
}

// ---------------- big MFMA GEMM: C[M,N] = A[M,K]@W[N,K]^T + b1 (+b2) -------
template <bool BF16OUT>
__global__ __launch_bounds__(256)
void gemm_bf16(const unsigned short* __restrict__ A,
               const unsigned short* __restrict__ W,
               const float* __restrict__ b1, const float* __restrict__ b2,
               void* __restrict__ Cv, int Mx, int Nx, int Kx) {
  __shared__ __align__(16) unsigned short As[128 * 40];
  __shared__ __align__(16) unsigned short Bs[128 * 40];
  const int tid  = threadIdx.x;
  const int m0   = blockIdx.y * 128;
  const int n0   = blockIdx.x * 128;
  const int w    = tid >> 6, lane = tid & 63;
  const int quad = lane >> 4, l15 = lane & 15;
  const int wm = (w & 1) * 64, wn = (w >> 1) * 64;

  f32x4 acc[4][4] = {};

  for (int k0 = 0; k0 < Kx; k0 += 32) {
#pragma unroll
    for (int i = 0; i < 2; ++i) {
      int c = tid + i * 256;
      int row = c >> 2, kc = c & 3;
      *(i32x4*)&As[row * 40 + kc * 8] =
          *(const i32x4*)&A[(size_t)(m0 + row) * Kx + k0 + kc * 8];
      *(i32x4*)&Bs[row * 40 + kc * 8] =
          *(const i32x4*)&W[(size_t)(n0 + row) * Kx + k0 + kc * 8];
    }
    __syncthreads();
    bf16x8 af[4], bg[4];
#pragma unroll
    for (int im = 0; im < 4; ++im)
      af[im] = *(const bf16x8*)&As[(wm + im * 16 + l15) * 40 + quad * 8];
#pragma unroll
    for (int in = 0; in < 4; ++in)
      bg[in] = *(const bf16x8*)&Bs[(wn + in * 16 + l15) * 40 + quad * 8];
#pragma unroll
    for (int im = 0; im < 4; ++im)
#pragma unroll
      for (int in = 0; in < 4; ++in)
        acc[im][in] = __builtin_amdgcn_mfma_f32_16x16x32_bf16(
            af[im], bg[in], acc[im][in], 0, 0, 0);
    __syncthreads();
  }

#pragma unroll
  for (int in = 0; in < 4; ++in) {
    int n = n0 + wn + in * 16 + l15;
    float bv = b1 ? b1[n] : 0.f;
    if (b2) bv += b2[n];
#pragma unroll
    for (int im = 0; im < 4; ++im) {
      int mb = m0 + wm + im * 16 + quad * 4;   // C/D: row = quad*4+reg, col = l15
#pragma unroll
      for (int r = 0; r < 4; ++r) {
        float val = acc[im][in][r] + bv;
        size_t o = (size_t)(mb + r) * Nx + n;
        if (BF16OUT) ((unsigned short*)Cv)[o] = f2bf(val);
        else         ((float*)Cv)[o] = val;
      }
    }
  }
}

// ---------------- fused dual-layer persistent recurrence -------------------
// Grid: 192 WGs x 256 thr (all co-resident; 1 WG/CU).
//   bx in [0,64):   layer-0 WG, 64 cols:  h0_t = tanh(pre0_t + h0_{t-1}@Whh0^T)
//   bx in [64,192): layer-1 WG, 32 cols:  h1_t = tanh(b + h0_t@Wih1^T
//                                                      + h1_{t-1}@Whh1^T)
// Group g owns batches [16g,16g+16). Wave w owns k-slice [256w,256w+256)
// (split-K, reduced through LDS). Weight fragments loaded once and PINNED in
// VGPRs via asm (fences can't force reload). Sync per round 2: tid0 polls the
// per-(layer,group,step) counter relaxed/agent, agent-acquire fence, barrier;
// h stored agent-scope (write-through to coherence point) and drained by the
// epilogue barrier's vmcnt(0) before the flag add.
__global__ __launch_bounds__(256, 1)
void rnn_fused(const unsigned short* __restrict__ Whh0,   // [H,H] bf16
               const unsigned short* __restrict__ Wih1,   // [H,H] bf16
               const unsigned short* __restrict__ Whh1,   // [H,H] bf16
               const unsigned short* __restrict__ pre0,   // [B,S,H] bf16
               const float* __restrict__ b_ih_1,
               const float* __restrict__ b_hh_1,
               unsigned short* __restrict__ h0seq,        // [B,S,H] bf16
               unsigned short* __restrict__ h1seq,        // [B,S,H] bf16
               unsigned int* __restrict__ flags)          // [2][4][S] zeroed
{
  const int bx   = blockIdx.x;
  const int tid  = threadIdx.x;
  const int w    = tid >> 6;        // wave = k-slice
  const int lane = tid & 63;
  const int quad = lane >> 4, l15 = lane & 15;

  __shared__ __align__(16) float q[4][4][16][20];  // [wave][ntile][col][4r pad20]

  if (bx < 64) {
    // ================= layer 0: 64 WGs, 64 cols =================
    const int g  = bx >> 4;
    const int n0 = (bx & 15) * 64;
    unsigned int* const f0 = flags + g * S_;

    i32x4 Wf[4][8];
    {
      const unsigned short* wp = Whh0 + (size_t)(n0 + l15) * H_ + w * 256 + quad * 8;
#pragma unroll
      for (int i = 0; i < 4; ++i)
#pragma unroll
        for (int kk = 0; kk < 8; ++kk)
          Wf[i][kk] = *(const i32x4*)(wp + (size_t)i * 16 * H_ + kk * 32);
    }
#pragma unroll
    for (int i = 0; i < 4; ++i)
#pragma unroll
      for (int kk = 0; kk < 8; ++kk)
        asm volatile("" : "+v"(Wf[i][kk]));   // pin: opaque, non-rematerializable

    for (int t = 0; t < S_; ++t) {
      float pv[4];   // pre0 prefetch (issues before the wait)
      {
        const unsigned short* pp = pre0 + (size_t)(g * 16 + quad * 4) * SH_ +
                                   (size_t)t * H_ + n0 + w * 16 + l15;
#pragma unroll
        for (int r = 0; r < 4; ++r) pv[r] = bf2f(pp[(size_t)r * SH_]);
      }

      f32x4 acc[4] = {};
      if (t > 0) {
        if (tid == 0) {
          while (__hip_atomic_load(&f0[t - 1], __ATOMIC_RELAXED,
                                   __HIP_MEMORY_SCOPE_AGENT) < 16u) {}
          __builtin_amdgcn_fence(__ATOMIC_ACQUIRE, "agent");
        }
        __syncthreads();
        const unsigned short* hp = h0seq + (size_t)(g * 16 + l15) * SH_ +
                                   (size_t)(t - 1) * H_ + w * 256 + quad * 8;
        bf16x8 Af[8];
#pragma unroll
        for (int kk = 0; kk < 8; ++kk) Af[kk] = *(const bf16x8*)(hp + kk * 32);
#pragma unroll
        for (int kk = 0; kk < 8; ++kk)
#pragma unroll
          for (int i = 0; i < 4; ++i)
            acc[i] = __builtin_amdgcn_mfma_f32_16x16x32_bf16(
                Af[kk], as_bf16x8(Wf[i][kk]), acc[i], 0, 0, 0);
      }

#pragma unroll
      for (int i = 0; i < 4; ++i) *(f32x4*)&q[w][i][l15][quad * 4] = acc[i];
      __syncthreads();
      f32x4 s = {};
#pragma unroll
      for (int wp2 = 0; wp2 < 4; ++wp2) {
        f32x4 v = *(const f32x4*)&q[wp2][w][l15][quad * 4];
#pragma unroll
        for (int r = 0; r < 4; ++r) s[r] += v[r];
      }

#pragma unroll
      for (int r = 0; r < 4; ++r) {
        unsigned short hb = f2bf(tanh_fast(pv[r] + s[r]));
        size_t o = (size_t)(g * 16 + quad * 4 + r) * SH_ + (size_t)t * H_ +
                   n0 + w * 16 + l15;
        __hip_atomic_store(&h0seq[o], hb, __ATOMIC_RELAXED,
                           __HIP_MEMORY_SCOPE_AGENT);
      }
      __syncthreads();   // vmcnt(0) drain of the agent stores; WAR on q
      if (tid == 0)
        __hip_atomic_fetch_add(&f0[t], 1u, __ATOMIC_RELAXED,
                               __HIP_MEMORY_SCOPE_AGENT);
    }
  } else {
    // ================= layer 1: 128 WGs, 32 cols =================
    const int id = bx - 64;
    const int g  = id >> 5;
    const int n0 = (id & 31) * 32;
    unsigned int* const f0 = flags + g * S_;
    unsigned int* const f1 = flags + 4 * S_ + g * S_;

    i32x4 Wi[2][8], Wr[2][8];
    {
      const unsigned short* wpi = Wih1 + (size_t)(n0 + l15) * H_ + w * 256 + quad * 8;
      const unsigned short* wpr = Whh1 + (size_t)(n0 + l15) * H_ + w * 256 + quad * 8;
#pragma unroll
      for (int i = 0; i < 2; ++i)
#pragma unroll
        for (int kk = 0; kk < 8; ++kk) {
          Wi[i][kk] = *(const i32x4*)(wpi + (size_t)i * 16 * H_ + kk * 32);
          Wr[i][kk] = *(const i32x4*)(wpr + (size_t)i * 16 * H_ + kk * 32);
        }
    }
#pragma unroll
    for (int i = 0; i < 2; ++i)
#pragma unroll
      for (int kk = 0; kk < 8; ++kk) {
        asm volatile("" : "+v"(Wi[i][kk]));
        asm volatile("" : "+v"(Wr[i][kk]));
      }

    float bias = 0.f;
    if (w < 2) {                         // epilogue col of this lane (waves 0,1)
      int n = n0 + w * 16 + l15;
      bias = b_ih_1[n] + b_hh_1[n];
    }

    for (int t = 0; t < S_; ++t) {
      f32x4 acc[2] = {};

      // --- input projection: wait h0_t (ready in steady state; off f1 chain)
      if (tid == 0) {
        while (__hip_atomic_load(&f0[t], __ATOMIC_RELAXED,
                                 __HIP_MEMORY_SCOPE_AGENT) < 16u) {}
        __builtin_amdgcn_fence(__ATOMIC_ACQUIRE, "agent");
      }
      __syncthreads();
      {
        const unsigned short* hp = h0seq + (size_t)(g * 16 + l15) * SH_ +
                                   (size_t)t * H_ + w * 256 + quad * 8;
        bf16x8 Af[8];
#pragma unroll
        for (int kk = 0; kk < 8; ++kk) Af[kk] = *(const bf16x8*)(hp + kk * 32);
#pragma unroll
        for (int kk = 0; kk < 8; ++kk)
#pragma unroll
          for (int i = 0; i < 2; ++i)
            acc[i] = __builtin_amdgcn_mfma_f32_16x16x32_bf16(
                Af[kk], as_bf16x8(Wi[i][kk]), acc[i], 0, 0, 0);
      }

      // --- recurrence: the serial chain (wait h1_{t-1})
      if (t > 0) {
        if (tid == 0) {
          while (__hip_atomic_load(&f1[t - 1], __ATOMIC_RELAXED,
                                   __HIP_MEMORY_SCOPE_AGENT) < 32u) {}
          __builtin_amdgcn_fence(__ATOMIC_ACQUIRE, "agent");
        }
        __syncthreads();
        const unsigned short* hp = h1seq + (size_t)(g * 16 + l15) * SH_ +
                                   (size_t)(t - 1) * H_ + w * 256 + quad * 8;
        bf16x8 Af[8];
#pragma unroll
        for (int kk = 0; kk < 8; ++kk) Af[kk] = *(const bf16x8*)(hp + kk * 32);
#pragma unroll
        for (int kk = 0; kk < 8; ++kk)
#pragma unroll
          for (int i = 0; i < 2; ++i)
            acc[i] = __builtin_amdgcn_mfma_f32_16x16x32_bf16(
                Af[kk], as_bf16x8(Wr[i][kk]), acc[i], 0, 0, 0);
      }

      // --- split-K reduce (2 ntiles -> waves 0,1 do the epilogue)
#pragma unroll
      for (int i = 0; i < 2; ++i) *(f32x4*)&q[w][i][l15][quad * 4] = acc[i];
      __syncthreads();
      if (w < 2) {
        f32x4 s = {};
#pragma unroll
        for (int wp2 = 0; wp2 < 4; ++wp2) {
          f32x4 v = *(const f32x4*)&q[wp2][w][l15][quad * 4];
#pragma unroll
          for (int r = 0; r < 4; ++r) s[r] += v[r];
        }
#pragma unroll
        for (int r = 0; r < 4; ++r) {
          unsigned short hb = f2bf(tanh_fast(bias + s[r]));
          size_t o = (size_t)(g * 16 + quad * 4 + r) * SH_ + (size_t)t * H_ +
                     n0 + w * 16 + l15;
          __hip_atomic_store(&h1seq[o], hb, __ATOMIC_RELAXED,
                             __HIP_MEMORY_SCOPE_AGENT);
        }
      }
      __syncthreads();   // vmcnt(0) drain (waves 0,1) before the flag add
      if (tid == 0)
        __hip_atomic_fetch_add(&f1[t], 1u, __ATOMIC_RELAXED,
                               __HIP_MEMORY_SCOPE_AGENT);
    }
  }
}

// ---------------------------------------------------------------------------
extern "C" void kernel_launch(void* const* d_in, const int* in_sizes, int n_in,
                              void* d_out, int out_size, void* d_ws, size_t ws_size,
                              hipStream_t stream) {
  const float* x      = (const float*)d_in[0];
  const float* W_ih_0 = (const float*)d_in[1];
  const float* W_hh_0 = (const float*)d_in[2];
  const float* b_ih_0 = (const float*)d_in[3];
  const float* b_hh_0 = (const float*)d_in[4];
  const float* W_ih_1 = (const float*)d_in[5];
  const float* W_hh_1 = (const float*)d_in[6];
  const float* b_ih_1 = (const float*)d_in[7];
  const float* b_hh_1 = (const float*)d_in[8];
  const float* fc_w   = (const float*)d_in[9];
  const float* fc_b   = (const float*)d_in[10];
  float* out = (float*)d_out;

  char* ws = (char*)d_ws;
  size_t off = 0;
  auto alloc = [&](size_t bytes) { char* p = ws + off; off += (bytes + 255) & ~(size_t)255; return p; };
  unsigned short* xb    = (unsigned short*)alloc((size_t)M_ * I_ * 2);   // 16.8 MB
  unsigned short* wih0b = (unsigned short*)alloc((size_t)H_ * I_ * 2);
  unsigned short* whh0b = (unsigned short*)alloc((size_t)H_ * H_ * 2);
  unsigned short* wih1b = (unsigned short*)alloc((size_t)H_ * H_ * 2);
  unsigned short* whh1b = (unsigned short*)alloc((size_t)H_ * H_ * 2);
  unsigned short* fcwb  = (unsigned short*)alloc((size_t)O_ * H_ * 2);
  unsigned int*   flags = (unsigned int*)alloc(2 * 4 * S_ * 4);          // 16 KB
  unsigned short* pre0b = (unsigned short*)alloc((size_t)M_ * H_ * 2);   // 67 MB
  unsigned short* h0seq = (unsigned short*)alloc((size_t)M_ * H_ * 2);   // 67 MB
  unsigned short* h1seq = (unsigned short*)alloc((size_t)M_ * H_ * 2);   // 67 MB

  hipMemsetAsync(flags, 0, 2 * 4 * S_ * 4, stream);

  auto cvt = [&](const float* s, unsigned short* d, int n) {
    int n4 = n / 4;
    cvt_bf16<<<(n4 + 255) / 256, 256, 0, stream>>>(s, d, n4);
  };
  cvt(x,      xb,    M_ * I_);
  cvt(W_ih_0, wih0b, H_ * I_);
  cvt(W_hh_0, whh0b, H_ * H_);
  cvt(W_ih_1, wih1b, H_ * H_);
  cvt(W_hh_1, whh1b, H_ * H_);
  cvt(fc_w,   fcwb,  O_ * H_);

  // pre0 = x @ W_ih0^T + b_ih0 + b_hh0  (bf16 out)
  gemm_bf16<true><<<dim3(H_ / 128, M_ / 128), 256, 0, stream>>>(
      xb, wih0b, b_ih_0, b_hh_0, pre0b, M_, H_, I_);

  // fused dual-layer recurrence (layer 1 pipelined one step behind layer 0)
  rnn_fused<<<192, 256, 0, stream>>>(whh0b, wih1b, whh1b, pre0b,
                                     b_ih_1, b_hh_1, h0seq, h1seq, flags);

  // FC head
  gemm_bf16<false><<<dim3(O_ / 128, M_ / 128), 256, 0, stream>>>(
      h1seq, fcwb, fc_b, nullptr, out, M_, O_, H_);
}